// Round 12
// baseline (120.879 us; speedup 1.0000x reference)
//
#include <hip/hip_runtime.h>

// Chamfer via MFMA v8-DIAG: v7 structure, hot loop repeated REPS=4x
// (min is idempotent -> output identical, absmax 0.0 expected).
// Purpose: make the main kernel outlast the harness's 40us poison fills so
// rocprof top-5 shows its VALUBusy/MfmaUtil/Occupancy/FETCH for the first
// time. Opaque per-rep base offset defeats CSE of loads/MFMAs across reps.

typedef __attribute__((ext_vector_type(8)))  short    bf16x8;
typedef __attribute__((ext_vector_type(16))) float    f32x16;
typedef __attribute__((ext_vector_type(4)))  unsigned uint32x4;

constexpr int NPTS   = 8192;
constexpr int COLS_W = 256;               // F-columns per wave (8 B-frags)
constexpr int COLS_B = COLS_W * 4;        // 1024 cols per 4-wave block
constexpr int N_CG   = NPTS / COLS_B;     // 8 column groups
constexpr int NSPLIT = 16;                // streamed-row split
constexpr int SROWS  = NPTS / NSPLIT;     // 512 rows per wave
constexpr int STEPS  = SROWS / 32;        // 16 steps
constexpr int REPS   = 4;                 // DIAG: x4 hot-loop repeat

__device__ inline float hi16f(float f) {            // truncation split (exact lo)
    return __uint_as_float(__float_as_uint(f) & 0xFFFF0000u);
}
// dword = bf16(hi_src)<<16 | bf16(lo_src)  (1x v_perm_b32, truncating)
__device__ inline unsigned pack2(float lo_src, float hi_src) {
    return __builtin_amdgcn_perm(__float_as_uint(hi_src),
                                 __float_as_uint(lo_src), 0x07060302u);
}

__global__ __launch_bounds__(256, 4) void chamfer_v8diag(
    const float* __restrict__ pred, const float* __restrict__ targ,
    float* __restrict__ part)
{
    const int lane = threadIdx.x & 63;
    const int wv   = threadIdx.x >> 6;
    const int l31  = lane & 31;
    const bool hi  = (lane >> 5) != 0;    // k-group: lo -> k0-7, hi -> k8-15
    const int mg   = blockIdx.x * 4 + wv; // 0..31 column group (256 cols)
    const int ns   = blockIdx.y;          // 0..NSPLIT-1
    const int db   = blockIdx.z;          // dir = db&1, b = db>>1
    const int dir  = db & 1, b = db >> 1;

    const float* F = (dir ? targ : pred) + (size_t)b * 3 * NPTS;
    const float* S = (dir ? pred : targ) + (size_t)b * 3 * NPTS;
    const unsigned ONE2 = 0x3F803F80u;    // bf16 1.0 | 1.0

    // ---- fixed side: 8 B-frags, -2 factors live here (built once) ----
    // B k lo: [1, 1, f2h, f2l, m2xh, m2xl, m2xh, m2yh]
    //   k hi: [m2yl, m2yh, m2zh, m2zl, m2zh, 0, 0, 0]
    bf16x8 bfr[8];
    #pragma unroll
    for (int j = 0; j < 8; ++j) {
        int c = mg * COLS_W + j * 32 + l31;
        float x = F[c], y = F[NPTS + c], z = F[2 * NPTS + c];
        float f2  = fmaf(x, x, fmaf(y, y, z * z));
        float m2x = -2.f * x, m2y = -2.f * y, m2z = -2.f * z;
        float f2l  = f2  - hi16f(f2);
        float m2xl = m2x - hi16f(m2x);
        float m2yl = m2y - hi16f(m2y);
        float m2zl = m2z - hi16f(m2z);
        uint32x4 d;
        d[0] = hi ? pack2(m2yl, m2y) : ONE2;
        d[1] = hi ? pack2(m2z, m2zl) : pack2(f2, f2l);
        d[2] = hi ? pack2(m2z, 0.f)  : pack2(m2x, m2xl);
        d[3] = hi ? 0u               : pack2(m2x, m2y);
        bfr[j] = __builtin_bit_cast(bf16x8, d);
    }

    // A k lo: [s2h, s2l, 1, 1, xh, xh, xl, yh]
    //   k hi: [yh, yl, zh, zh, zl, 0, 0, 0]      (branchless: cndmask)
    auto build_af = [&](float x, float y, float z) -> bf16x8 {
        float s2  = fmaf(x, x, fmaf(y, y, z * z));
        float s2l = s2 - hi16f(s2);
        float xl  = x - hi16f(x);
        float yl  = y - hi16f(y);
        float zl  = z - hi16f(z);
        uint32x4 d;
        d[0] = hi ? pack2(y, yl)  : pack2(s2, s2l);
        d[1] = hi ? pack2(z, z)   : ONE2;
        d[2] = hi ? pack2(zl, 0.f): pack2(x, x);
        d[3] = hi ? 0u            : pack2(xl, y);
        return __builtin_bit_cast(bf16x8, d);
    };

    f32x16 zero;
    #pragma unroll
    for (int i = 0; i < 16; ++i) zero[i] = 0.f;

    const float INF = __int_as_float(0x7F800000);
    float a0 = INF, a1 = INF, a2 = INF, a3 = INF;
    float a4 = INF, a5 = INF, a6 = INF, a7 = INF;

    // min over the 16 regs (16 rows of this lane-half): 8x v_min3
    auto tree = [](float acc, const f32x16& c) -> float {
        float t0 = fminf(fminf(c[0],  c[1]),  c[2]);
        float t1 = fminf(fminf(c[3],  c[4]),  c[5]);
        float t2 = fminf(fminf(c[6],  c[7]),  c[8]);
        float t3 = fminf(fminf(c[9],  c[10]), c[11]);
        float t4 = fminf(fminf(c[12], c[13]), c[14]);
        float r0 = fminf(fminf(t0, t1), t2);
        float r1 = fminf(fminf(t3, t4), c[15]);
        return fminf(fminf(r0, r1), acc);
    };

    const float* S0 = S + (size_t)ns * SROWS + l31;
    const float* S1 = S0 + NPTS;
    const float* S2 = S0 + 2 * NPTS;

    // one step: 8 MFMA + 8 trees, <=2 C-tiles live
    auto step = [&](float x, float y, float z) {
        bf16x8 af = build_af(x, y, z);
        f32x16 c0 = __builtin_amdgcn_mfma_f32_32x32x16_bf16(af, bfr[0], zero, 0, 0, 0);
        f32x16 c1 = __builtin_amdgcn_mfma_f32_32x32x16_bf16(af, bfr[1], zero, 0, 0, 0);
        a0 = tree(a0, c0);
        c0 = __builtin_amdgcn_mfma_f32_32x32x16_bf16(af, bfr[2], zero, 0, 0, 0);
        a1 = tree(a1, c1);
        c1 = __builtin_amdgcn_mfma_f32_32x32x16_bf16(af, bfr[3], zero, 0, 0, 0);
        a2 = tree(a2, c0);
        c0 = __builtin_amdgcn_mfma_f32_32x32x16_bf16(af, bfr[4], zero, 0, 0, 0);
        a3 = tree(a3, c1);
        c1 = __builtin_amdgcn_mfma_f32_32x32x16_bf16(af, bfr[5], zero, 0, 0, 0);
        a4 = tree(a4, c0);
        c0 = __builtin_amdgcn_mfma_f32_32x32x16_bf16(af, bfr[6], zero, 0, 0, 0);
        a5 = tree(a5, c1);
        c1 = __builtin_amdgcn_mfma_f32_32x32x16_bf16(af, bfr[7], zero, 0, 0, 0);
        a6 = tree(a6, c0);
        a7 = tree(a7, c1);
    };

    // DIAG: repeat the hot loop REPS times; min is idempotent so the result
    // is unchanged. Opaque base defeats CSE of loads/MFMAs across reps.
    #pragma unroll 1
    for (int rep = 0; rep < REPS; ++rep) {
        int base = 0;
        asm volatile("" : "+v"(base));        // opaque 0
        float cx = S0[base], cy = S1[base], cz = S2[base];
        for (int s = 0; s < STEPS - 1; ++s) {
            int o = base + (s + 1) * 32;
            float nx = S0[o], ny = S1[o], nz = S2[o];
            step(cx, cy, cz);
            cx = nx; cy = ny; cz = nz;
        }
        step(cx, cy, cz);
    }

    // combine lane-halves (lo regs hold 16 rows, hi the complementary 16)
    a0 = fminf(a0, __shfl_xor(a0, 32));
    a1 = fminf(a1, __shfl_xor(a1, 32));
    a2 = fminf(a2, __shfl_xor(a2, 32));
    a3 = fminf(a3, __shfl_xor(a3, 32));
    a4 = fminf(a4, __shfl_xor(a4, 32));
    a5 = fminf(a5, __shfl_xor(a5, 32));
    a6 = fminf(a6, __shfl_xor(a6, 32));
    a7 = fminf(a7, __shfl_xor(a7, 32));

    if (lane < 32) {
        float* dst = part + ((size_t)db * NSPLIT + ns) * NPTS + (size_t)mg * COLS_W;
        dst[l31]       = a0;
        dst[32  + l31] = a1;
        dst[64  + l31] = a2;
        dst[96  + l31] = a3;
        dst[128 + l31] = a4;
        dst[160 + l31] = a5;
        dst[192 + l31] = a6;
        dst[224 + l31] = a7;
    }
}

// min over NSPLIT partials, sqrt, mean, sum both directions
__global__ __launch_bounds__(256) void reduce_k(
    const float* __restrict__ part, float* __restrict__ out)
{
    int tid = blockIdx.x * 256 + threadIdx.x;   // 0..65535
    int db  = tid >> 13;
    int m   = tid & (NPTS - 1);
    const float* base = part + (size_t)db * NSPLIT * NPTS + m;
    float v = base[0];
    #pragma unroll
    for (int nsh = 1; nsh < NSPLIT; ++nsh)
        v = fminf(v, base[(size_t)nsh * NPTS]);
    float d = sqrtf(fmaxf(v, 0.f)) * (1.0f / 32768.0f);
    for (int off = 32; off; off >>= 1) d += __shfl_down(d, off);
    __shared__ float wsum[4];
    if ((threadIdx.x & 63) == 0) wsum[threadIdx.x >> 6] = d;
    __syncthreads();
    if (threadIdx.x == 0) atomicAdd(out, wsum[0] + wsum[1] + wsum[2] + wsum[3]);
}

extern "C" void kernel_launch(void* const* d_in, const int* in_sizes, int n_in,
                              void* d_out, int out_size, void* d_ws, size_t ws_size,
                              hipStream_t stream) {
    const float* pred = (const float*)d_in[0];
    const float* targ = (const float*)d_in[1];
    float* out  = (float*)d_out;
    float* part = (float*)d_ws;   // 8 * NSPLIT * NPTS * 4 = 4 MB

    hipMemsetAsync(d_out, 0, sizeof(float), stream);

    dim3 grid(N_CG, NSPLIT, 8);   // 8 x 16 x 8 = 1024 blocks x 4 waves
    chamfer_v8diag<<<grid, 256, 0, stream>>>(pred, targ, part);

    reduce_k<<<(8 * NPTS) / 256, 256, 0, stream>>>(part, out);
}

// Round 13
// 82.043 us; speedup vs baseline: 1.4734x; 1.4734x over previous
//
#include <hip/hip_runtime.h>

// Chamfer via MFMA v9: streamed side pre-packed to a ws table (pack kernel,
// bit-identical to the in-kernel pack -> absmax 0.0 preserved), hot loop =
// 1 dwordx4 load (prefetch distance 2) + 8 MFMA + 64 v_min3 per step.
// Fixed side (8 B-frags) still built in-kernel once per block.

typedef __attribute__((ext_vector_type(8)))  short    bf16x8;
typedef __attribute__((ext_vector_type(16))) float    f32x16;
typedef __attribute__((ext_vector_type(4)))  unsigned uint32x4;

constexpr int NPTS   = 8192;
constexpr int BATCH  = 4;
constexpr int COLS_W = 256;               // F-columns per wave (8 B-frags)
constexpr int COLS_B = COLS_W * 4;        // 1024 cols per 4-wave block
constexpr int N_CG   = NPTS / COLS_B;     // 8 column groups
constexpr int NSPLIT = 16;                // streamed-row split
constexpr int SROWS  = NPTS / NSPLIT;     // 512 rows per wave
constexpr int STEPS  = SROWS / 32;        // 16 steps

// ws: [0,1MB) A-table pred; [1MB,2MB) A-table targ; [2MB,6MB) part buffer
constexpr size_t TBLA     = (size_t)BATCH * NPTS * 32;   // 1 MB per set
constexpr size_t PART_OFF = 2 * TBLA;

__device__ inline float hi16f(float f) {            // truncation split (exact lo)
    return __uint_as_float(__float_as_uint(f) & 0xFFFF0000u);
}
// dword = bf16(hi_src)<<16 | bf16(lo_src)  (1x v_perm_b32, truncating)
__device__ inline unsigned pack2(float lo_src, float hi_src) {
    return __builtin_amdgcn_perm(__float_as_uint(hi_src),
                                 __float_as_uint(lo_src), 0x07060302u);
}

// ---------------- pack A-layout (streamed-side) table, both sets ----------
// A k lo: [s2h, s2l, 1, 1, xh, xh, xl, yh]   (dwords 0-3)
//   k hi: [yh, yl, zh, zh, zl, 0, 0, 0]      (dwords 4-7)
__global__ __launch_bounds__(256) void pack_a(
    const float* __restrict__ pred, const float* __restrict__ targ,
    unsigned* __restrict__ wsa)
{
    int tid = blockIdx.x * 256 + threadIdx.x;   // 0..65535
    int which = tid >> 15;                      // 0: pred, 1: targ
    int r = tid & 32767;
    int b = r >> 13, m = r & (NPTS - 1);
    const float* src = which ? targ : pred;
    const float* sb = src + (size_t)b * 3 * NPTS;
    float x = sb[m], y = sb[NPTS + m], z = sb[2 * NPTS + m];
    float s2  = fmaf(x, x, fmaf(y, y, z * z));
    float s2l = s2 - hi16f(s2);
    float xl  = x - hi16f(x);
    float yl  = y - hi16f(y);
    float zl  = z - hi16f(z);
    const unsigned ONE2 = 0x3F803F80u;
    uint4 lo = make_uint4(pack2(s2, s2l), ONE2, pack2(x, x), pack2(xl, y));
    uint4 hi = make_uint4(pack2(y, yl), pack2(z, z), pack2(zl, 0.f), 0u);
    uint4* dst = (uint4*)wsa;
    dst[(size_t)tid * 2]     = lo;
    dst[(size_t)tid * 2 + 1] = hi;
}

// ---------------- main kernel ----------------
__global__ __launch_bounds__(256, 4) void chamfer_v9(
    const float* __restrict__ pred, const float* __restrict__ targ,
    const unsigned* __restrict__ wsa, float* __restrict__ part)
{
    const int lane = threadIdx.x & 63;
    const int wv   = threadIdx.x >> 6;
    const int l31  = lane & 31;
    const bool hi  = (lane >> 5) != 0;    // k-group: lo -> k0-7, hi -> k8-15
    const int mg   = blockIdx.x * 4 + wv; // 0..31 column group (256 cols)
    const int ns   = blockIdx.y;          // 0..NSPLIT-1
    const int db   = blockIdx.z;          // dir = db&1, b = db>>1
    const int dir  = db & 1, b = db >> 1;

    const float* F = (dir ? targ : pred) + (size_t)b * 3 * NPTS;
    const unsigned ONE2 = 0x3F803F80u;    // bf16 1.0 | 1.0

    // ---- fixed side: 8 B-frags, -2 factors live here (built once) ----
    // B k lo: [1, 1, f2h, f2l, m2xh, m2xl, m2xh, m2yh]
    //   k hi: [m2yl, m2yh, m2zh, m2zl, m2zh, 0, 0, 0]
    bf16x8 bfr[8];
    #pragma unroll
    for (int j = 0; j < 8; ++j) {
        int c = mg * COLS_W + j * 32 + l31;
        float x = F[c], y = F[NPTS + c], z = F[2 * NPTS + c];
        float f2  = fmaf(x, x, fmaf(y, y, z * z));
        float m2x = -2.f * x, m2y = -2.f * y, m2z = -2.f * z;
        float f2l  = f2  - hi16f(f2);
        float m2xl = m2x - hi16f(m2x);
        float m2yl = m2y - hi16f(m2y);
        float m2zl = m2z - hi16f(m2z);
        uint32x4 d;
        d[0] = hi ? pack2(m2yl, m2y) : ONE2;
        d[1] = hi ? pack2(m2z, m2zl) : pack2(f2, f2l);
        d[2] = hi ? pack2(m2z, 0.f)  : pack2(m2x, m2xl);
        d[3] = hi ? 0u               : pack2(m2x, m2y);
        bfr[j] = __builtin_bit_cast(bf16x8, d);
    }

    f32x16 zero;
    #pragma unroll
    for (int i = 0; i < 16; ++i) zero[i] = 0.f;

    const float INF = __int_as_float(0x7F800000);
    float a0 = INF, a1 = INF, a2 = INF, a3 = INF;
    float a4 = INF, a5 = INF, a6 = INF, a7 = INF;

    // min over the 16 regs (16 rows of this lane-half): 8x v_min3
    auto tree = [](float acc, const f32x16& c) -> float {
        float t0 = fminf(fminf(c[0],  c[1]),  c[2]);
        float t1 = fminf(fminf(c[3],  c[4]),  c[5]);
        float t2 = fminf(fminf(c[6],  c[7]),  c[8]);
        float t3 = fminf(fminf(c[9],  c[10]), c[11]);
        float t4 = fminf(fminf(c[12], c[13]), c[14]);
        float r0 = fminf(fminf(t0, t1), t2);
        float r1 = fminf(fminf(t3, t4), c[15]);
        return fminf(fminf(r0, r1), acc);
    };

    // streamed side: packed A-table (dir0 streams targ -> table 1, dir1 pred)
    const char* abase = (const char*)wsa + (dir ? 0 : TBLA)
        + (size_t)b * NPTS * 32
        + ((size_t)ns * SROWS + (size_t)l31) * 32 + (size_t)(hi ? 16 : 0);
    auto lda = [&](int s) -> bf16x8 {
        return *reinterpret_cast<const bf16x8*>(abase + (size_t)s * 1024);
    };

    // one step: 8 MFMA + 8 trees, <=2 C-tiles live
    auto step = [&](bf16x8 af) {
        f32x16 c0 = __builtin_amdgcn_mfma_f32_32x32x16_bf16(af, bfr[0], zero, 0, 0, 0);
        f32x16 c1 = __builtin_amdgcn_mfma_f32_32x32x16_bf16(af, bfr[1], zero, 0, 0, 0);
        a0 = tree(a0, c0);
        c0 = __builtin_amdgcn_mfma_f32_32x32x16_bf16(af, bfr[2], zero, 0, 0, 0);
        a1 = tree(a1, c1);
        c1 = __builtin_amdgcn_mfma_f32_32x32x16_bf16(af, bfr[3], zero, 0, 0, 0);
        a2 = tree(a2, c0);
        c0 = __builtin_amdgcn_mfma_f32_32x32x16_bf16(af, bfr[4], zero, 0, 0, 0);
        a3 = tree(a3, c1);
        c1 = __builtin_amdgcn_mfma_f32_32x32x16_bf16(af, bfr[5], zero, 0, 0, 0);
        a4 = tree(a4, c0);
        c0 = __builtin_amdgcn_mfma_f32_32x32x16_bf16(af, bfr[6], zero, 0, 0, 0);
        a5 = tree(a5, c1);
        c1 = __builtin_amdgcn_mfma_f32_32x32x16_bf16(af, bfr[7], zero, 0, 0, 0);
        a6 = tree(a6, c0);
        a7 = tree(a7, c1);
    };

    // prefetch distance 2: ~2 steps (~280 cyc) covers L2 latency
    bf16x8 p0 = lda(0), p1 = lda(1);
    for (int s = 0; s + 2 < STEPS; ++s) {
        bf16x8 nx = lda(s + 2);
        step(p0);
        p0 = p1; p1 = nx;
    }
    step(p0);
    step(p1);

    // combine lane-halves (lo regs hold 16 rows, hi the complementary 16)
    a0 = fminf(a0, __shfl_xor(a0, 32));
    a1 = fminf(a1, __shfl_xor(a1, 32));
    a2 = fminf(a2, __shfl_xor(a2, 32));
    a3 = fminf(a3, __shfl_xor(a3, 32));
    a4 = fminf(a4, __shfl_xor(a4, 32));
    a5 = fminf(a5, __shfl_xor(a5, 32));
    a6 = fminf(a6, __shfl_xor(a6, 32));
    a7 = fminf(a7, __shfl_xor(a7, 32));

    if (lane < 32) {
        float* dst = part + ((size_t)db * NSPLIT + ns) * NPTS + (size_t)mg * COLS_W;
        dst[l31]       = a0;
        dst[32  + l31] = a1;
        dst[64  + l31] = a2;
        dst[96  + l31] = a3;
        dst[128 + l31] = a4;
        dst[160 + l31] = a5;
        dst[192 + l31] = a6;
        dst[224 + l31] = a7;
    }
}

// min over NSPLIT partials, sqrt, mean, sum both directions
__global__ __launch_bounds__(256) void reduce_k(
    const float* __restrict__ part, float* __restrict__ out)
{
    int tid = blockIdx.x * 256 + threadIdx.x;   // 0..65535
    int db  = tid >> 13;
    int m   = tid & (NPTS - 1);
    const float* base = part + (size_t)db * NSPLIT * NPTS + m;
    float v = base[0];
    #pragma unroll
    for (int nsh = 1; nsh < NSPLIT; ++nsh)
        v = fminf(v, base[(size_t)nsh * NPTS]);
    float d = sqrtf(fmaxf(v, 0.f)) * (1.0f / 32768.0f);
    for (int off = 32; off; off >>= 1) d += __shfl_down(d, off);
    __shared__ float wsum[4];
    if ((threadIdx.x & 63) == 0) wsum[threadIdx.x >> 6] = d;
    __syncthreads();
    if (threadIdx.x == 0) atomicAdd(out, wsum[0] + wsum[1] + wsum[2] + wsum[3]);
}

extern "C" void kernel_launch(void* const* d_in, const int* in_sizes, int n_in,
                              void* d_out, int out_size, void* d_ws, size_t ws_size,
                              hipStream_t stream) {
    const float* pred = (const float*)d_in[0];
    const float* targ = (const float*)d_in[1];
    float* out = (float*)d_out;
    char* ws = (char*)d_ws;
    unsigned* wsa = (unsigned*)ws;              // 2 MB A-tables
    float* part   = (float*)(ws + PART_OFF);    // 4 MB partials

    hipMemsetAsync(d_out, 0, sizeof(float), stream);

    pack_a<<<(2 * BATCH * NPTS) / 256, 256, 0, stream>>>(pred, targ, wsa);

    dim3 grid(N_CG, NSPLIT, 8);   // 8 x 16 x 8 = 1024 blocks x 4 waves
    chamfer_v9<<<grid, 256, 0, stream>>>(pred, targ, wsa, part);

    reduce_k<<<(8 * NPTS) / 256, 256, 0, stream>>>(part, out);
}

// Round 14
// 76.475 us; speedup vs baseline: 1.5806x; 1.0728x over previous
//
#include <hip/hip_runtime.h>

// Chamfer via MFMA v10: single self-contained main kernel.
// Each block owns (column-group, row-slice, dir, batch): packs its 512-row
// streamed slice into 16KB LDS (conflict-free stride-32), builds 4 fixed-side
// B-frags in registers, then hot loop = ds_read_b128 + 4 MFMA + 32 v_min3.
// 2048 blocks x 4 waves, bounds(256,8) -> 8 waves/SIMD (VGPR <= 64, ~54 est).
// d2 = s2 + f2 - 2 s.f via K=16 bf16 hi/lo split (absmax 0.0, R3..R13).

typedef __attribute__((ext_vector_type(8)))  short    bf16x8;
typedef __attribute__((ext_vector_type(16))) float    f32x16;
typedef __attribute__((ext_vector_type(4)))  unsigned uint32x4;

constexpr int NPTS   = 8192;
constexpr int COLS_W = 128;               // F-columns per wave (4 B-frags)
constexpr int COLS_B = COLS_W * 4;        // 512 cols per 4-wave block
constexpr int N_CG   = NPTS / COLS_B;     // 16 column groups
constexpr int NSPLIT = 16;                // streamed-row split
constexpr int SROWS  = NPTS / NSPLIT;     // 512 rows per block
constexpr int STEPS  = SROWS / 32;        // 16 steps

__device__ inline float hi16f(float f) {            // truncation split (exact lo)
    return __uint_as_float(__float_as_uint(f) & 0xFFFF0000u);
}
// dword = bf16(hi_src)<<16 | bf16(lo_src)  (1x v_perm_b32, truncating)
__device__ inline unsigned pack2(float lo_src, float hi_src) {
    return __builtin_amdgcn_perm(__float_as_uint(hi_src),
                                 __float_as_uint(lo_src), 0x07060302u);
}

__global__ __launch_bounds__(256, 8) void chamfer_v10(
    const float* __restrict__ pred, const float* __restrict__ targ,
    float* __restrict__ part)
{
    __shared__ char slds[SROWS * 32];     // 16 KB: row r at r*32 (lo16B|hi16B)

    const int tid  = threadIdx.x;
    const int lane = tid & 63;
    const int wv   = tid >> 6;
    const int l31  = lane & 31;
    const bool hi  = (lane >> 5) != 0;    // k-group: lo -> k0-7, hi -> k8-15
    const int mg   = blockIdx.x * 4 + wv; // 0..63 column group (128 cols)
    const int ns   = blockIdx.y;          // 0..NSPLIT-1
    const int db   = blockIdx.z;          // dir = db&1, b = db>>1
    const int dir  = db & 1, b = db >> 1;

    const float* F = (dir ? targ : pred) + (size_t)b * 3 * NPTS;
    const float* S = (dir ? pred : targ) + (size_t)b * 3 * NPTS;
    const unsigned ONE2 = 0x3F803F80u;    // bf16 1.0 | 1.0

    // ---- pack this block's 512-row streamed slice into LDS ----
    // A k lo: [s2h, s2l, 1, 1, xh, xh, xl, yh]  (16B)
    //   k hi: [yh, yl, zh, zh, zl, 0, 0, 0]     (16B)
    for (int r = tid; r < SROWS; r += 256) {
        int m = ns * SROWS + r;
        float x = S[m], y = S[NPTS + m], z = S[2 * NPTS + m];
        float s2  = fmaf(x, x, fmaf(y, y, z * z));
        float s2l = s2 - hi16f(s2);
        float xl  = x - hi16f(x);
        float yl  = y - hi16f(y);
        float zl  = z - hi16f(z);
        uint4 lo = make_uint4(pack2(s2, s2l), ONE2, pack2(x, x), pack2(xl, y));
        uint4 hh = make_uint4(pack2(y, yl), pack2(z, z), pack2(zl, 0.f), 0u);
        *reinterpret_cast<uint4*>(&slds[r * 32])      = lo;
        *reinterpret_cast<uint4*>(&slds[r * 32 + 16]) = hh;
    }

    // ---- fixed side: 4 B-frags, -2 factors live here (built once) ----
    // B k lo: [1, 1, f2h, f2l, m2xh, m2xl, m2xh, m2yh]
    //   k hi: [m2yl, m2yh, m2zh, m2zl, m2zh, 0, 0, 0]
    bf16x8 bfr[4];
    #pragma unroll
    for (int j = 0; j < 4; ++j) {
        int c = mg * COLS_W + j * 32 + l31;
        float x = F[c], y = F[NPTS + c], z = F[2 * NPTS + c];
        float f2  = fmaf(x, x, fmaf(y, y, z * z));
        float m2x = -2.f * x, m2y = -2.f * y, m2z = -2.f * z;
        float f2l  = f2  - hi16f(f2);
        float m2xl = m2x - hi16f(m2x);
        float m2yl = m2y - hi16f(m2y);
        float m2zl = m2z - hi16f(m2z);
        uint32x4 d;
        d[0] = hi ? pack2(m2yl, m2y) : ONE2;
        d[1] = hi ? pack2(m2z, m2zl) : pack2(f2, f2l);
        d[2] = hi ? pack2(m2z, 0.f)  : pack2(m2x, m2xl);
        d[3] = hi ? 0u               : pack2(m2x, m2y);
        bfr[j] = __builtin_bit_cast(bf16x8, d);
    }

    f32x16 zero;
    #pragma unroll
    for (int i = 0; i < 16; ++i) zero[i] = 0.f;

    const float INF = __int_as_float(0x7F800000);
    float a0 = INF, a1 = INF, a2 = INF, a3 = INF;

    // min over the 16 regs (16 rows of this lane-half): 8x v_min3
    auto tree = [](float acc, const f32x16& c) -> float {
        float t0 = fminf(fminf(c[0],  c[1]),  c[2]);
        float t1 = fminf(fminf(c[3],  c[4]),  c[5]);
        float t2 = fminf(fminf(c[6],  c[7]),  c[8]);
        float t3 = fminf(fminf(c[9],  c[10]), c[11]);
        float t4 = fminf(fminf(c[12], c[13]), c[14]);
        float r0 = fminf(fminf(t0, t1), t2);
        float r1 = fminf(fminf(t3, t4), c[15]);
        return fminf(fminf(r0, r1), acc);
    };

    __syncthreads();

    // ---- hot loop: 1 ds_read_b128 + 4 MFMA + 32 v_min3 per step ----
    // one live C-tile (VGPR diet for 8 waves/SIMD); TLP covers the RAW chain
    const int aoff = l31 * 32 + (hi ? 16 : 0);
    for (int s = 0; s < STEPS; ++s) {
        bf16x8 af = *reinterpret_cast<const bf16x8*>(&slds[s * 1024 + aoff]);
        f32x16 c;
        c = __builtin_amdgcn_mfma_f32_32x32x16_bf16(af, bfr[0], zero, 0, 0, 0);
        a0 = tree(a0, c);
        c = __builtin_amdgcn_mfma_f32_32x32x16_bf16(af, bfr[1], zero, 0, 0, 0);
        a1 = tree(a1, c);
        c = __builtin_amdgcn_mfma_f32_32x32x16_bf16(af, bfr[2], zero, 0, 0, 0);
        a2 = tree(a2, c);
        c = __builtin_amdgcn_mfma_f32_32x32x16_bf16(af, bfr[3], zero, 0, 0, 0);
        a3 = tree(a3, c);
    }

    // combine lane-halves (lo regs hold 16 rows, hi the complementary 16)
    a0 = fminf(a0, __shfl_xor(a0, 32));
    a1 = fminf(a1, __shfl_xor(a1, 32));
    a2 = fminf(a2, __shfl_xor(a2, 32));
    a3 = fminf(a3, __shfl_xor(a3, 32));

    if (lane < 32) {
        float* dst = part + ((size_t)db * NSPLIT + ns) * NPTS + (size_t)mg * COLS_W;
        dst[l31]      = a0;
        dst[32 + l31] = a1;
        dst[64 + l31] = a2;
        dst[96 + l31] = a3;
    }
}

// min over NSPLIT partials, sqrt, mean, sum both directions
__global__ __launch_bounds__(256) void reduce_k(
    const float* __restrict__ part, float* __restrict__ out)
{
    int tid = blockIdx.x * 256 + threadIdx.x;   // 0..65535
    int db  = tid >> 13;
    int m   = tid & (NPTS - 1);
    const float* base = part + (size_t)db * NSPLIT * NPTS + m;
    float v = base[0];
    #pragma unroll
    for (int nsh = 1; nsh < NSPLIT; ++nsh)
        v = fminf(v, base[(size_t)nsh * NPTS]);
    float d = sqrtf(fmaxf(v, 0.f)) * (1.0f / 32768.0f);
    for (int off = 32; off; off >>= 1) d += __shfl_down(d, off);
    __shared__ float wsum[4];
    if ((threadIdx.x & 63) == 0) wsum[threadIdx.x >> 6] = d;
    __syncthreads();
    if (threadIdx.x == 0) atomicAdd(out, wsum[0] + wsum[1] + wsum[2] + wsum[3]);
}

extern "C" void kernel_launch(void* const* d_in, const int* in_sizes, int n_in,
                              void* d_out, int out_size, void* d_ws, size_t ws_size,
                              hipStream_t stream) {
    const float* pred = (const float*)d_in[0];
    const float* targ = (const float*)d_in[1];
    float* out  = (float*)d_out;
    float* part = (float*)d_ws;   // 8 * NSPLIT * NPTS * 4 = 4 MB

    hipMemsetAsync(d_out, 0, sizeof(float), stream);

    dim3 grid(N_CG, NSPLIT, 8);   // 16 x 16 x 8 = 2048 blocks x 4 waves
    chamfer_v10<<<grid, 256, 0, stream>>>(pred, targ, part);

    reduce_k<<<(8 * NPTS) / 256, 256, 0, stream>>>(part, out);
}